// Round 1
// baseline (311.102 us; speedup 1.0000x reference)
//
#include <hip/hip_runtime.h>

// Problem shape (fixed by setup_inputs): B=1024, T=2048, A=64.
// Outputs concatenated flat: equity_curve [B][T+1] then net_return [B][T].
#define PB 1024
#define PT 2048
#define PA 64
#define PC 32          // chunks along T
#define PL 64          // PT / PC, timesteps per chunk

static constexpr float TX_COST = 0.001f;

// Phase 1: one wave (64 lanes) per (b, c) chunk. Lane a owns asset a.
// Writes net_return[b, t0..t0+L) and UNSCALED local cumprod into equity slots,
// plus the chunk product P[b*C + c] to workspace.
__global__ __launch_bounds__(256) void p1_chunk_scan(
    const float* __restrict__ alloc, const float* __restrict__ rets,
    float* __restrict__ eq,      // [B][T+1] region of d_out
    float* __restrict__ nr_out,  // [B][T]   region of d_out
    float* __restrict__ P)       // [B*C] chunk products (workspace)
{
    int wid  = (int)((blockIdx.x * (unsigned)blockDim.x + threadIdx.x) >> 6);
    int lane = threadIdx.x & 63;
    int b = wid / PC;
    int c = wid % PC;
    int t0 = c * PL;

    const float* ap = alloc + (((size_t)b * PT + t0) << 6) + lane;
    const float* rp = rets  + (((size_t)b * PT + t0) << 6) + lane;

    // prev_alloc for the first step of this chunk: zeros at t=0, else row t0-1.
    float prev = (c == 0) ? 0.0f : ap[-64];
    float prod = 1.0f;

    float* nrp = nr_out + (size_t)b * PT + t0;
    float* eqp = eq     + (size_t)b * (PT + 1) + 1 + t0;

#pragma unroll 4
    for (int i = 0; i < PL; ++i) {
        float va = ap[(size_t)i * 64];
        float vr = rp[(size_t)i * 64];
        float d = fabsf(va - prev);
        float p = va * vr;
        // 64-lane butterfly: both sums land in every lane.
#pragma unroll
        for (int off = 1; off < 64; off <<= 1) {
            d += __shfl_xor(d, off, 64);
            p += __shfl_xor(p, off, 64);
        }
        float nr = p - d * TX_COST;
        prod *= (1.0f + nr);
        if (lane == 0) {
            nrp[i] = nr;
            eqp[i] = prod;   // local (per-chunk) cumprod; scaled in phase 3
        }
        prev = va;
    }
    if (lane == 0) P[b * PC + c] = prod;
}

// Phase 2: per row, exclusive prefix product over the C chunk products.
__global__ __launch_bounds__(256) void p2_prefix(
    const float* __restrict__ P, float* __restrict__ S)
{
    int b = (int)(blockIdx.x * (unsigned)blockDim.x + threadIdx.x);
    if (b >= PB) return;
    float p = 1.0f;
#pragma unroll
    for (int c = 0; c < PC; ++c) {
        S[b * PC + c] = p;
        p *= P[b * PC + c];
    }
}

// Phase 3: scale each equity slot by its chunk's prefix; write the 1.0 column.
__global__ __launch_bounds__(256) void p3_scale(
    float* __restrict__ eq, const float* __restrict__ S)
{
    int idx = (int)(blockIdx.x * (unsigned)blockDim.x + threadIdx.x);
    if (idx >= PB * PT) return;
    int b = idx >> 11;          // idx / T
    int t = idx & (PT - 1);     // idx % T
    float s = S[b * PC + (t >> 6)];   // t / L
    size_t e = (size_t)b * (PT + 1) + 1 + t;
    eq[e] *= s;
    if (t == 0) eq[(size_t)b * (PT + 1)] = 1.0f;
}

extern "C" void kernel_launch(void* const* d_in, const int* in_sizes, int n_in,
                              void* d_out, int out_size, void* d_ws, size_t ws_size,
                              hipStream_t stream) {
    const float* alloc = (const float*)d_in[0];
    const float* rets  = (const float*)d_in[1];
    float* eq     = (float*)d_out;                       // [B][T+1]
    float* nr_out = eq + (size_t)PB * (PT + 1);          // [B][T]
    float* P = (float*)d_ws;                             // [B*C]
    float* S = P + (size_t)PB * PC;                      // [B*C]

    // Phase 1: B*C waves = 32768 waves -> 8192 blocks of 256.
    {
        int waves = PB * PC;
        int blocks = waves * 64 / 256;
        p1_chunk_scan<<<blocks, 256, 0, stream>>>(alloc, rets, eq, nr_out, P);
    }
    // Phase 2: one thread per row.
    p2_prefix<<<(PB + 255) / 256, 256, 0, stream>>>(P, S);
    // Phase 3: one thread per (b, t).
    {
        int n = PB * PT;
        p3_scale<<<(n + 255) / 256, 256, 0, stream>>>(eq, S);
    }
}

// Round 2
// 233.173 us; speedup vs baseline: 1.3342x; 1.3342x over previous
//
#include <hip/hip_runtime.h>

// Problem shape (fixed by setup_inputs): B=1024, T=2048, A=64.
// Outputs concatenated flat: equity_curve [B][T+1] then net_return [B][T].
#define PB 1024
#define PT 2048
#define PA 64
#define PC 32          // chunks along T
#define PL 64          // PT / PC, timesteps per wave

static constexpr float TX_COST = 0.001f;

// Phase 1: one wave per (b, chunk-of-64-t). Per iteration the wave loads a
// contiguous 1 KiB block = 4 timestep rows (float4, 16 B/lane, fully
// coalesced). lane = tg*16 + cq: thread owns assets [cq*4, cq*4+4) of
// timestep t0+4i+tg. Per-lane partial of (port_return - TX*turnover) is
// reduced over 16 lanes (4 shuffles); chunk-local cumprod fused via a
// 2-step group scan. Writes net_return, local-cumprod equity, chunk product.
__global__ __launch_bounds__(256) void p1_chunk_scan(
    const float4* __restrict__ A4, const float4* __restrict__ R4,
    float* __restrict__ eq,      // [B][T+1] region of d_out
    float* __restrict__ nr_out,  // [B][T]   region of d_out
    float* __restrict__ P)       // [B*C] chunk products (workspace)
{
    int wid  = (int)((blockIdx.x * (unsigned)blockDim.x + threadIdx.x) >> 6);
    int lane = threadIdx.x & 63;
    int b = wid >> 5;          // / PC
    int c = wid & (PC - 1);
    int t0 = c * PL;
    int tg = lane >> 4;        // which of the 4 rows in this block
    int cq = lane & 15;        // which float4 chunk of the row

    const size_t rowbase = ((size_t)b * PT + t0) * 16;   // float4 units
    float* nrp = nr_out + (size_t)b * PT + t0;
    float* eqp = eq     + (size_t)b * (PT + 1) + 1 + t0;

    float carry = 1.0f;

#pragma unroll 4
    for (int i = 0; i < PL / 4; ++i) {
        int trow = t0 + i * 4 + tg;
        size_t idx = rowbase + (size_t)i * 64 + lane;
        float4 a4 = A4[idx];
        float4 r4 = R4[idx];
        float4 pa4;
        if (trow == 0) pa4 = make_float4(0.f, 0.f, 0.f, 0.f);
        else           pa4 = A4[idx - 16];          // row t-1: L1 hit

        float d = fabsf(a4.x - pa4.x) + fabsf(a4.y - pa4.y)
                + fabsf(a4.z - pa4.z) + fabsf(a4.w - pa4.w);
        float p = a4.x * r4.x + a4.y * r4.y + a4.z * r4.z + a4.w * r4.w;
        // net_return is linear in both partials: reduce one combined value.
        float q = p - d * TX_COST;
#pragma unroll
        for (int off = 1; off < 16; off <<= 1)
            q += __shfl_xor(q, off, 64);
        // q == net_return for timestep trow, identical across the 16-lane group
        float s = 1.0f + q;
        // inclusive prefix product over the 4 row-groups
        float pp = s;
        float u = __shfl_up(pp, 16, 64); if (tg >= 1) pp *= u;
        u       = __shfl_up(pp, 32, 64); if (tg >= 2) pp *= u;
        float tot = __shfl(pp, 63, 64);
        if (cq == 0) {
            nrp[i * 4 + tg] = q;
            eqp[i * 4 + tg] = carry * pp;   // chunk-local cumprod
        }
        carry *= tot;
    }
    if (lane == 0) P[wid] = carry;
}

// Phase 2: per row, exclusive prefix product over the C chunk products.
__global__ __launch_bounds__(256) void p2_prefix(
    const float* __restrict__ P, float* __restrict__ S)
{
    int b = (int)(blockIdx.x * (unsigned)blockDim.x + threadIdx.x);
    if (b >= PB) return;
    float p = 1.0f;
#pragma unroll
    for (int c = 0; c < PC; ++c) {
        S[b * PC + c] = p;
        p *= P[b * PC + c];
    }
}

// Phase 3: scale each equity slot by its chunk's prefix; write the 1.0 column.
__global__ __launch_bounds__(256) void p3_scale(
    float* __restrict__ eq, const float* __restrict__ S)
{
    int idx = (int)(blockIdx.x * (unsigned)blockDim.x + threadIdx.x);
    if (idx >= PB * PT) return;
    int b = idx >> 11;          // idx / T
    int t = idx & (PT - 1);     // idx % T
    float s = S[b * PC + (t >> 6)];   // t / L
    size_t e = (size_t)b * (PT + 1) + 1 + t;
    eq[e] *= s;
    if (t == 0) eq[(size_t)b * (PT + 1)] = 1.0f;
}

extern "C" void kernel_launch(void* const* d_in, const int* in_sizes, int n_in,
                              void* d_out, int out_size, void* d_ws, size_t ws_size,
                              hipStream_t stream) {
    const float4* A4 = (const float4*)d_in[0];
    const float4* R4 = (const float4*)d_in[1];
    float* eq     = (float*)d_out;                       // [B][T+1]
    float* nr_out = eq + (size_t)PB * (PT + 1);          // [B][T]
    float* P = (float*)d_ws;                             // [B*C]
    float* S = P + (size_t)PB * PC;                      // [B*C]

    // Phase 1: B*C waves = 32768 waves -> 8192 blocks of 256.
    {
        int waves = PB * PC;
        int blocks = waves * 64 / 256;
        p1_chunk_scan<<<blocks, 256, 0, stream>>>(A4, R4, eq, nr_out, P);
    }
    // Phase 2: one thread per row.
    p2_prefix<<<(PB + 255) / 256, 256, 0, stream>>>(P, S);
    // Phase 3: one thread per (b, t).
    {
        int n = PB * PT;
        p3_scale<<<(n + 255) / 256, 256, 0, stream>>>(eq, S);
    }
}

// Round 3
// 231.325 us; speedup vs baseline: 1.3449x; 1.0080x over previous
//
#include <hip/hip_runtime.h>

// Problem shape (fixed by setup_inputs): B=1024, T=2048, A=64.
// Outputs concatenated flat: equity_curve [B][T+1] then net_return [B][T].
#define PB 1024
#define PT 2048
#define PA 64
#define NW 16          // waves per block (one block per row)
#define LW 128         // timesteps per wave-chunk = PT/NW
#define NIT 32         // LW/4 iterations per wave

static constexpr float TX_COST = 0.001f;

// One block per row b. Wave w owns timesteps [w*128, (w+1)*128).
// Per iteration the wave loads a contiguous 1 KiB block = 4 timestep rows
// (float4, 16 B/lane, fully coalesced). lane = tg*16+cq: thread owns assets
// [cq*4, cq*4+4) of timestep t0+4i+tg. The combined per-lane partial of
// (port_return - TX*turnover) is reduced over 16 lanes, the 4 timesteps'
// (1+nr) factors are scanned across tg-groups, and chunk-local cumprods +
// net_returns are parked in LDS. After one barrier, each thread folds the 16
// chunk products into its prefix and streams out eq/nr fully coalesced.
__global__ __launch_bounds__(1024) void fused_sim(
    const float4* __restrict__ A4, const float4* __restrict__ R4,
    float* __restrict__ eq,       // [B][T+1] region of d_out
    float* __restrict__ nr_out)   // [B][T]   region of d_out
{
    __shared__ float s_eq[PT];    // chunk-local cumprod per timestep
    __shared__ float s_nr[PT];    // net_return per timestep
    __shared__ float s_P[NW];     // per-wave chunk products

    int b    = blockIdx.x;
    int w    = threadIdx.x >> 6;
    int lane = threadIdx.x & 63;
    int tg   = lane >> 4;         // which of the 4 rows in the 1 KiB block
    int cq   = lane & 15;         // which float4 of the row
    int t0   = w * LW;

    const size_t rowbase = ((size_t)b * PT + t0) * 16;   // float4 units

    float carry = 1.0f;
#pragma unroll 4
    for (int i = 0; i < NIT; ++i) {
        int trow = t0 + i * 4 + tg;
        size_t idx = rowbase + (size_t)i * 64 + lane;
        float4 a4 = A4[idx];
        float4 r4 = R4[idx];
        float4 pa4;
        if (trow == 0) pa4 = make_float4(0.f, 0.f, 0.f, 0.f);
        else           pa4 = A4[idx - 16];          // row t-1: L1/L2 hit

        float d = fabsf(a4.x - pa4.x) + fabsf(a4.y - pa4.y)
                + fabsf(a4.z - pa4.z) + fabsf(a4.w - pa4.w);
        float p = a4.x * r4.x + a4.y * r4.y + a4.z * r4.z + a4.w * r4.w;
        float q = p - d * TX_COST;            // linear: reduce combined value
#pragma unroll
        for (int off = 1; off < 16; off <<= 1)
            q += __shfl_xor(q, off, 64);
        // q == net_return(trow), identical across the 16-lane group
        float s = 1.0f + q;
        float pp = s;                          // inclusive scan over tg
        float u = __shfl_up(pp, 16, 64); if (tg >= 1) pp *= u;
        u       = __shfl_up(pp, 32, 64); if (tg >= 2) pp *= u;
        float tot = __shfl(pp, 63, 64);
        if (cq == 0) {
            s_nr[t0 + i * 4 + tg] = q;
            s_eq[t0 + i * 4 + tg] = carry * pp;
        }
        carry *= tot;
    }
    if (lane == 0) s_P[w] = carry;
    __syncthreads();

    // Phase B: thread tid handles timesteps tid and tid+1024.
    int tid = threadIdx.x;
    int c0 = tid >> 7;                         // chunk of first position
    float s0 = 1.0f;
    for (int j = 0; j < c0; ++j) s0 *= s_P[j];         // S[c0]
    float s1 = s0;
    for (int j = c0; j < c0 + 8; ++j) s1 *= s_P[j];    // S[c0+8]

    float* eqrow = eq     + (size_t)b * (PT + 1);
    float* nrrow = nr_out + (size_t)b * PT;
    eqrow[1 + tid]        = s0 * s_eq[tid];
    eqrow[1 + 1024 + tid] = s1 * s_eq[1024 + tid];
    nrrow[tid]            = s_nr[tid];
    nrrow[1024 + tid]     = s_nr[1024 + tid];
    if (tid == 0) eqrow[0] = 1.0f;
}

extern "C" void kernel_launch(void* const* d_in, const int* in_sizes, int n_in,
                              void* d_out, int out_size, void* d_ws, size_t ws_size,
                              hipStream_t stream) {
    const float4* A4 = (const float4*)d_in[0];
    const float4* R4 = (const float4*)d_in[1];
    float* eq     = (float*)d_out;                       // [B][T+1]
    float* nr_out = eq + (size_t)PB * (PT + 1);          // [B][T]

    fused_sim<<<PB, 1024, 0, stream>>>(A4, R4, eq, nr_out);
}